// Round 14
// baseline (921.949 us; speedup 1.0000x reference)
//
#include <hip/hip_runtime.h>
#include <math.h>

// b=16, C=512, H=W=56, wsz=7, X=Y=8, nw=64/img, n=49, tokens=50, heads=16, dhead=32
#define SCALE_D 0.17677669529663687f  // 32^-0.5

typedef __attribute__((ext_vector_type(8))) short short8;
typedef __attribute__((ext_vector_type(4))) float f32x4;

__device__ __forceinline__ unsigned short f2bf(float f) {
  unsigned u = __builtin_bit_cast(unsigned, f);
  unsigned r = u + 0x7FFF + ((u >> 16) & 1);
  return (unsigned short)(r >> 16);
}
__device__ __forceinline__ float bf2f(unsigned short h) {
  unsigned u = ((unsigned)h) << 16;
  return __builtin_bit_cast(float, u);
}
__device__ __forceinline__ void gload16(const void* g, void* l) {
  __builtin_amdgcn_global_load_lds((const __attribute__((address_space(1))) unsigned int*)g,
                                   (__attribute__((address_space(3))) unsigned int*)l,
                                   16, 0, 0);
}

// -------- split f32 -> bf16 hi/lo planes ------------------------------------------
__global__ __launch_bounds__(256) void k_split(const float* __restrict__ src,
                                               unsigned short* __restrict__ hi,
                                               unsigned short* __restrict__ lo, int n) {
  int i = blockIdx.x * 256 + threadIdx.x;
  if (i < n) {
    float v = src[i];
    unsigned short h = f2bf(v);
    hi[i] = h;
    lo[i] = f2bf(v - bf2f(h));
  }
}

// -------- gather Xc^T chunk (4 images) as bf16 hi/lo [12800][512] ------------------
__global__ __launch_bounds__(256) void k_build_xcT(const float* __restrict__ x,
                                                   const float* __restrict__ wtok,
                                                   unsigned short* __restrict__ Thi,
                                                   unsigned short* __restrict__ Tlo,
                                                   int bb0) {
  const int cblk = blockIdx.x;   // 0..7
  const int h    = blockIdx.y;   // 0..55 pixels, 56 = token-0 pass
  const int bbL  = blockIdx.z;   // 0..3
  const int bb   = bb0 + bbL;
  const int tid  = threadIdx.x;
  const int c0   = cblk * 64;
  if (h == 56) {
    for (int e = tid; e < 4096; e += 256) {
      int wl = e >> 6, cl = e & 63;
      float v = wtok[c0 + cl];
      unsigned short hv = f2bf(v);
      long idx = ((long)(bbL * 64 + wl) * 50) * 512 + c0 + cl;
      Thi[idx] = hv;
      Tlo[idx] = f2bf(v - bf2f(hv));
    }
    return;
  }
  __shared__ unsigned short shi[64][57], slo[64][57];
  const int Xw = h / 7, r7 = h % 7;
  for (int e = tid; e < 3584; e += 256) {
    int cl = e / 56, w = e - cl * 56;
    float v = x[((long)(bb * 512 + c0 + cl) * 56 + h) * 56 + w];
    unsigned short hv = f2bf(v);
    shi[cl][w] = hv;
    slo[cl][w] = f2bf(v - bf2f(hv));
  }
  __syncthreads();
  for (int e = tid; e < 3584; e += 256) {
    int row = e >> 6, cl = e & 63;       // row = Yw*7+c7
    int Yw = row / 7, c7 = row - Yw * 7;
    long trow = (long)(bbL * 64 + Xw * 8 + Yw) * 50 + 1 + r7 * 7 + c7;
    Thi[trow * 512 + c0 + cl] = shi[cl][row];
    Tlo[trow * 512 + c0 + cl] = slo[cl][row];
  }
}

// -------- split-bf16 MFMA GEMM: A DIRECT from global (L2-hot weights), B via LDS --
// C = A(f32~hi+lo) * B^T(rows=[n][k]); tile 128x128, BK=32, 3-pass split-bf16.
// LDS = B hi/lo dbuf only (32 KB) -> 4 blocks/CU (16 waves) for TLP; counted
// vmcnt(4) leaves next B-stage in flight; A frags global->reg each step (L2 hit,
// hidden by 4 waves/SIMD). j-outer MFMA loop caps VGPR (~124).
template <int PACK>
__global__ __launch_bounds__(256, 4) void k_gemm_mfma(
    const unsigned short* __restrict__ Ahi, const unsigned short* __restrict__ Alo,
    const unsigned short* __restrict__ Bhi, const unsigned short* __restrict__ Blo,
    float* __restrict__ C, const float* __restrict__ bias,
    int NC, int brow_stride, long c_stride) {
  __shared__ unsigned short lds[2][2][128][32];  // 2 bufs x {Bhi,Blo} = 32 KB
  const int tid = threadIdx.x;
  const int wv = tid >> 6, lane = tid & 63;

  // hw dispatch id -> chunked logical id (m204): B-panel sharers on one XCD
  const int gy = gridDim.y;
  const int nwg = gridDim.x * gy;
  int hw = blockIdx.y * gridDim.x + blockIdx.x;
  int flat;
  {
    int q = nwg >> 3, r = nwg & 7;
    int xcd = hw & 7, k = hw >> 3;
    int start = (xcd < r) ? xcd * (q + 1) : r * (q + 1) + (xcd - r) * q;
    flat = start + k;
  }
  const int bx = flat / gy, by = flat % gy;
  const int m0 = by * 128, n0 = bx * 128;
  const long brow0 = (long)blockIdx.z * brow_stride + n0;
  C += (long)blockIdx.z * c_stride;

  const int wr = wv >> 1, wc = wv & 1;
  const int lr = lane & 15, kb = lane >> 4;
  const int srow = lane >> 2, sju = lane & 3;
  const int sswz = (sju ^ ((srow >> 1) & 3)) * 8;   // pre-swizzled src slot (B)
  const int ca = (kb ^ ((lr >> 1) & 3)) * 8;        // read-side xor (0-conflict)
  const long arow = (long)(m0 + wr * 64 + lr) * 512 + kb * 8;  // A frag base

  f32x4 acc[4][4];
#pragma unroll
  for (int i = 0; i < 4; ++i)
#pragma unroll
    for (int j = 0; j < 4; ++j) {
      f32x4 z = {0.f, 0.f, 0.f, 0.f};
      acc[i][j] = z;
    }

  auto STAGE_B = [&](int buf, int k0) {  // 4 gload_lds per wave
#pragma unroll
    for (int it = 0; it < 2; ++it) {
      const int rloc = wv * 32 + it * 16;
      const long gb = (brow0 + rloc + srow) * 512 + k0 + sswz;
      gload16(Bhi + gb, &lds[buf][0][rloc][0]);
      gload16(Blo + gb, &lds[buf][1][rloc][0]);
    }
  };

  STAGE_B(0, 0);
  int cur = 0;
  for (int t = 0; t < 16; ++t) {
    const int k0 = t * 32;
    // A fragments for THIS step: 8 x global_load_dwordx4 (issued before stage so
    // vmcnt(4) drains them together with B(t), leaving B(t+1) in flight)
    short8 ah[4], al[4];
#pragma unroll
    for (int f = 0; f < 4; ++f) {
      const long ga = arow + (long)f * 16 * 512 + k0;
      ah[f] = *(const short8*)&Ahi[ga];
      al[f] = *(const short8*)&Alo[ga];
    }
    if (t < 15) {
      STAGE_B(cur ^ 1, k0 + 32);
      asm volatile("s_waitcnt vmcnt(4)" ::: "memory");  // B(t)+A(t) done; B(t+1) flies
    } else {
      asm volatile("s_waitcnt vmcnt(0)" ::: "memory");
    }
    __builtin_amdgcn_s_barrier();
    asm volatile("" ::: "memory");
#pragma unroll
    for (int j = 0; j < 4; ++j) {       // j-outer: only 2 B-frags live at a time
      int rb = wc * 64 + j * 16 + lr;
      const short8 bh = *(const short8*)&lds[cur][0][rb][ca];
      const short8 bl = *(const short8*)&lds[cur][1][rb][ca];
#pragma unroll
      for (int i = 0; i < 4; ++i) {
        acc[i][j] = __builtin_amdgcn_mfma_f32_16x16x32_bf16(ah[i], bh, acc[i][j], 0, 0, 0);
        acc[i][j] = __builtin_amdgcn_mfma_f32_16x16x32_bf16(ah[i], bl, acc[i][j], 0, 0, 0);
        acc[i][j] = __builtin_amdgcn_mfma_f32_16x16x32_bf16(al[i], bh, acc[i][j], 0, 0, 0);
      }
    }
    asm volatile("s_waitcnt lgkmcnt(0)" ::: "memory");
    __builtin_amdgcn_s_barrier();
    asm volatile("" ::: "memory");
    cur ^= 1;
  }

#pragma unroll
  for (int i = 0; i < 4; ++i)
#pragma unroll
    for (int nf = 0; nf < 4; ++nf) {
      int col = n0 + wc * 64 + nf * 16 + lr;
      if (col < NC) {
#pragma unroll
        for (int j4 = 0; j4 < 4; ++j4) {
          int row = m0 + wr * 64 + i * 16 + kb * 4 + j4;
          float v = acc[i][nf][j4];
          if (PACK) {
            unsigned short h = f2bf(v);
            unsigned short l = f2bf(v - bf2f(h));
            ((unsigned*)C)[(long)row * NC + col] = (unsigned)h | ((unsigned)l << 16);
          } else {
            C[(long)row * NC + col] = v + (bias ? bias[row] : 0.f);
          }
        }
      }
    }
}

// -------- stage-1 attention, MFMA, one wave per (window, head) ---------------------
__global__ __launch_bounds__(256) void k_attn1_mfma(const unsigned* __restrict__ QKV,
                                                    float* __restrict__ OUT1, int w0) {
  __shared__ unsigned short P[4][16][72];
  const int tid = threadIdx.x;
  const int wv = tid >> 6, lane = tid & 63;
  const int idx = blockIdx.x * 4 + wv;     // wl*16 + h
  const int wl = idx >> 4, h = idx & 15;
  const int lr = lane & 15, kb = lane >> 4;
  const long tb = (long)wl * 50;

  short8 kh[4], kl[4];
#pragma unroll
  for (int jt = 0; jt < 4; ++jt) {
#pragma unroll
    for (int e = 0; e < 8; ++e) {
      unsigned u = QKV[(long)(512 + h * 32 + kb * 8 + e) * 12800 + tb + jt * 16 + lr];
      kh[jt][e] = (short)(u & 0xFFFF);
      kl[jt][e] = (short)(u >> 16);
    }
  }
  short8 vh[2][2], vl[2][2];
#pragma unroll
  for (int ddt = 0; ddt < 2; ++ddt)
#pragma unroll
    for (int ks = 0; ks < 2; ++ks) {
      const long vb = (long)(1024 + h * 32 + ddt * 16 + lr) * 12800 + tb + ks * 32 + kb * 8;
#pragma unroll
      for (int e = 0; e < 8; ++e) {
        int j = ks * 32 + kb * 8 + e;
        unsigned u = (j < 50) ? QKV[vb + e] : 0u;
        vh[ddt][ks][e] = (short)(u & 0xFFFF);
        vl[ddt][ks][e] = (short)(u >> 16);
      }
    }

  const long ob = (long)((w0 + wl) * 16 + h) * 1600;

  for (int it = 0; it < 4; ++it) {
    short8 qh, ql;
#pragma unroll
    for (int e = 0; e < 8; ++e) {
      unsigned u = QKV[(long)(h * 32 + kb * 8 + e) * 12800 + tb + it * 16 + lr];
      qh[e] = (short)(u & 0xFFFF);
      ql[e] = (short)(u >> 16);
    }
    f32x4 s[4];
#pragma unroll
    for (int jt = 0; jt < 4; ++jt) {
      f32x4 z = {0.f, 0.f, 0.f, 0.f};
      s[jt] = z;
      s[jt] = __builtin_amdgcn_mfma_f32_16x16x32_bf16(qh, kh[jt], s[jt], 0, 0, 0);
      s[jt] = __builtin_amdgcn_mfma_f32_16x16x32_bf16(qh, kl[jt], s[jt], 0, 0, 0);
      s[jt] = __builtin_amdgcn_mfma_f32_16x16x32_bf16(ql, kh[jt], s[jt], 0, 0, 0);
#pragma unroll
      for (int r = 0; r < 4; ++r) s[jt][r] *= SCALE_D;
    }
    if (lr >= 2) {
#pragma unroll
      for (int r = 0; r < 4; ++r) s[3][r] = -1e30f;
    }
    float ex[4][4], rinv[4];
#pragma unroll
    for (int r = 0; r < 4; ++r) {
      float m = fmaxf(fmaxf(s[0][r], s[1][r]), fmaxf(s[2][r], s[3][r]));
      m = fmaxf(m, __shfl_xor(m, 1));
      m = fmaxf(m, __shfl_xor(m, 2));
      m = fmaxf(m, __shfl_xor(m, 4));
      m = fmaxf(m, __shfl_xor(m, 8));
      float sm = 0.f;
#pragma unroll
      for (int jt = 0; jt < 4; ++jt) {
        ex[jt][r] = __expf(s[jt][r] - m);
        sm += ex[jt][r];
      }
      sm += __shfl_xor(sm, 1);
      sm += __shfl_xor(sm, 2);
      sm += __shfl_xor(sm, 4);
      sm += __shfl_xor(sm, 8);
      rinv[r] = 1.f / sm;
    }
#pragma unroll
    for (int jt = 0; jt < 4; ++jt)
#pragma unroll
      for (int r = 0; r < 4; ++r)
        P[wv][kb * 4 + r][jt * 16 + lr] = f2bf(ex[jt][r] * rinv[r]);
    short8 pa0 = *(const short8*)&P[wv][lr][kb * 8];
    short8 pa1 = *(const short8*)&P[wv][lr][32 + kb * 8];
    f32x4 o[2];
#pragma unroll
    for (int ddt = 0; ddt < 2; ++ddt) {
      f32x4 z = {0.f, 0.f, 0.f, 0.f};
      o[ddt] = z;
      o[ddt] = __builtin_amdgcn_mfma_f32_16x16x32_bf16(pa0, vh[ddt][0], o[ddt], 0, 0, 0);
      o[ddt] = __builtin_amdgcn_mfma_f32_16x16x32_bf16(pa0, vl[ddt][0], o[ddt], 0, 0, 0);
      o[ddt] = __builtin_amdgcn_mfma_f32_16x16x32_bf16(pa1, vh[ddt][1], o[ddt], 0, 0, 0);
      o[ddt] = __builtin_amdgcn_mfma_f32_16x16x32_bf16(pa1, vl[ddt][1], o[ddt], 0, 0, 0);
    }
#pragma unroll
    for (int ddt = 0; ddt < 2; ++ddt)
#pragma unroll
      for (int r = 0; r < 4; ++r) {
        int i = it * 16 + kb * 4 + r;
        if (i < 50) OUT1[ob + i * 32 + ddt * 16 + lr] = o[ddt][r];
      }
  }
}

// -------- f32 GEMM (small qk projection) -------------------------------------------
__global__ __launch_bounds__(256) void k_gemm(const float* __restrict__ A,
                                              const float* __restrict__ Bg,
                                              float* __restrict__ C,
                                              const float* __restrict__ bias,
                                              int M, int N, int K, long sB, long sC) {
  Bg += (long)blockIdx.z * sB;
  C  += (long)blockIdx.z * sC;
  __shared__ __align__(16) float As[32][132];
  __shared__ __align__(16) float Bs[32][132];
  const int tid = threadIdx.x;
  const int tx = tid & 15, ty = tid >> 4;
  const int m0 = blockIdx.y * 128, n0 = blockIdx.x * 128;

  float acc[8][8];
#pragma unroll
  for (int q = 0; q < 8; ++q)
#pragma unroll
    for (int r = 0; r < 8; ++r) acc[q][r] = 0.f;

  for (int k0 = 0; k0 < K; k0 += 32) {
#pragma unroll
    for (int it = 0; it < 4; ++it) {
      int idx = tid + it * 256;
      int row = idx >> 3, c4 = idx & 7;
      const float4 f = *(const float4*)&A[(long)(m0 + row) * K + k0 + c4 * 4];
      As[c4 * 4 + 0][row] = f.x;
      As[c4 * 4 + 1][row] = f.y;
      As[c4 * 4 + 2][row] = f.z;
      As[c4 * 4 + 3][row] = f.w;
    }
#pragma unroll
    for (int it = 0; it < 4; ++it) {
      int idx = tid + it * 256;
      int row = idx >> 5, c4 = idx & 31;
      int col = n0 + c4 * 4;
      float4 f;
      if (col + 3 < N) {
        f = *(const float4*)&Bg[(long)(k0 + row) * N + col];
      } else {
        f.x = (col + 0 < N) ? Bg[(long)(k0 + row) * N + col + 0] : 0.f;
        f.y = (col + 1 < N) ? Bg[(long)(k0 + row) * N + col + 1] : 0.f;
        f.z = (col + 2 < N) ? Bg[(long)(k0 + row) * N + col + 2] : 0.f;
        f.w = (col + 3 < N) ? Bg[(long)(k0 + row) * N + col + 3] : 0.f;
      }
      *(float4*)&Bs[row][c4 * 4] = f;
    }
    __syncthreads();
#pragma unroll
    for (int kk = 0; kk < 32; ++kk) {
      const float4 a0 = *(const float4*)&As[kk][ty * 8];
      const float4 a1 = *(const float4*)&As[kk][ty * 8 + 4];
      const float4 b0 = *(const float4*)&Bs[kk][tx * 8];
      const float4 b1 = *(const float4*)&Bs[kk][tx * 8 + 4];
      const float am[8] = {a0.x, a0.y, a0.z, a0.w, a1.x, a1.y, a1.z, a1.w};
      const float bn[8] = {b0.x, b0.y, b0.z, b0.w, b1.x, b1.y, b1.z, b1.w};
#pragma unroll
      for (int q = 0; q < 8; ++q)
#pragma unroll
        for (int r = 0; r < 8; ++r) acc[q][r] += am[q] * bn[r];
    }
    __syncthreads();
  }

#pragma unroll
  for (int q = 0; q < 8; ++q) {
    int m = m0 + ty * 8 + q;
    float bv = bias ? bias[m] : 0.f;
#pragma unroll
    for (int half = 0; half < 8; half += 4) {
      int col = n0 + tx * 8 + half;
#pragma unroll
      for (int rr = 0; rr < 4; ++rr)
        if (col + rr < N) C[(long)m * N + col + rr] = acc[q][half + rr] + bv;
    }
  }
}

// -------- LayerNorm + exact GELU on window tokens ----------------------------------
__global__ __launch_bounds__(256) void k_ln_gelu(const float* __restrict__ OUT1,
                                                 const float* __restrict__ lnw,
                                                 const float* __restrict__ lnb,
                                                 float* __restrict__ G) {
  const int tid = threadIdx.x;
  const int r = blockIdx.x * 8 + (tid >> 5);
  const int l = tid & 31;
  const int bb = r >> 10, hh = (r >> 6) & 15, wp = r & 63;
  float v = OUT1[((long)((bb * 64 + wp) * 16 + hh)) * 1600 + l];
  float s = v, s2 = v * v;
#pragma unroll
  for (int o = 16; o >= 1; o >>= 1) {
    s += __shfl_xor(s, o, 32);
    s2 += __shfl_xor(s2, o, 32);
  }
  float mu = s * (1.f / 32.f);
  float var = s2 * (1.f / 32.f) - mu * mu;
  float xn = (v - mu) * rsqrtf(var + 1e-5f) * lnw[l] + lnb[l];
  float g = 0.5f * xn * (1.f + erff(xn * 0.70710678118654752f));
  G[((long)(bb * 512 + hh * 32 + l)) * 64 + wp] = g;
}

// -------- stage-2 attention + MFMA aggregation -------------------------------------
__global__ __launch_bounds__(256) void k_attn2_mfma(const float* __restrict__ QK,
                                                    const float* __restrict__ OUT1,
                                                    float* __restrict__ AGG) {
  const int bh = blockIdx.x;
  const int bb = bh >> 4, hh = bh & 15;
  const int tid = threadIdx.x;
  const int wv = tid >> 6, lane = tid & 63;
  const int lr = lane & 15, kb = lane >> 4;
  const int wr = wv >> 1, wc = wv & 1;

  __shared__ float wqs[64 * 33], wks[64 * 33];
  __shared__ float sd[64 * 65];
  __shared__ float smx[64], ssum[64];
  __shared__ __align__(16) unsigned short PAh[64][72], PAl[64][72];  // P[i][wp]
  __shared__ __align__(16) unsigned short VTh[64][72], VTl[64][72];  // V^T[jd][wp]

  for (int t = tid; t < 2048; t += 256) {
    int dd = t >> 6, i = t & 63;
    wqs[i * 33 + dd] = QK[((long)(bb * 1024 + hh * 64 + dd)) * 64 + i] * SCALE_D;
    wks[i * 33 + dd] = QK[((long)(bb * 1024 + hh * 64 + 32 + dd)) * 64 + i];
  }
  __syncthreads();
  for (int t = tid; t < 4096; t += 256) {
    int i = t >> 6, j = t & 63;
    float s = 0.f;
#pragma unroll
    for (int dd = 0; dd < 32; ++dd) s += wqs[i * 33 + dd] * wks[j * 33 + dd];
    sd[i * 65 + j] = s;
  }
  __syncthreads();
  if (tid < 64) {
    float mx = -1e30f;
    for (int j = 0; j < 64; ++j) mx = fmaxf(mx, sd[tid * 65 + j]);
    float sm = 0.f;
    for (int j = 0; j < 64; ++j) sm += expf(sd[tid * 65 + j] - mx);
    smx[tid] = mx;
    ssum[tid] = 1.f / sm;
  }
  __syncthreads();
  for (int t = tid; t < 4096; t += 256) {
    int i = t >> 6, j = t & 63;
    float p = expf(sd[i * 65 + j] - smx[i]) * ssum[i];
    unsigned short h = f2bf(p);
    PAh[i][j] = h;
    PAl[i][j] = f2bf(p - bf2f(h));
  }
  __syncthreads();

  const int jstart = blockIdx.y * 13;                 // y=0: 0..12, y=1: 13..24
  const int ntiles = (blockIdx.y == 0) ? 13 : 12;
  const int swp = tid >> 2, sq = tid & 3;
  const long vbase = ((long)((bb * 64 + swp) * 16 + hh)) * 1600 + 32;
  const long abase = (long)bh * 100352;

  for (int tt = 0; tt < ntiles; ++tt) {
    const int jt = jstart + tt;
    const int jd0 = jt * 64;
    const int JT = (jt == 24) ? 32 : 64;
    for (int jj = 0; jj < (JT >> 4); ++jj) {
      const float4 v4 = *(const float4*)&OUT1[vbase + jd0 + jj * 16 + sq * 4];
#pragma unroll
      for (int e = 0; e < 4; ++e) {
        int jl = jj * 16 + sq * 4 + e;
        float v = (e == 0) ? v4.x : (e == 1) ? v4.y : (e == 2) ? v4.z : v4.w;
        unsigned short h = f2bf(v);
        VTh[jl][swp] = h;
        VTl[jl][swp] = f2bf(v - bf2f(h));
      }
    }
    __syncthreads();
#pragma unroll
    for (int mt = 0; mt < 2; ++mt) {
      const int i0 = wr * 32 + mt * 16;
#pragma unroll
      for (int nt = 0; nt < 2; ++nt) {
        const int jl0 = wc * 32 + nt * 16;
        if (jl0 < JT) {
          f32x4 acc = {0.f, 0.f, 0.f, 0.f};
#pragma unroll
          for (int ks = 0; ks < 2; ++ks) {
            const short8 pah = *(const short8*)&PAh[i0 + lr][ks * 32 + kb * 8];
            const short8 pal = *(const short8*)&PAl[i0 + lr][ks * 32 + kb * 8];
            const short8 vth = *(const short8*)&VTh[jl0 + lr][ks * 32 + kb * 8];
            const short8 vtl = *(const short8*)&VTl[jl0 + lr][ks * 32 + kb * 8];
            acc = __builtin_amdgcn_mfma_f32_16x16x32_bf16(pah, vth, acc, 0, 0, 0);
            acc = __builtin_amdgcn_mfma_f32_16x16x32_bf16(pah, vtl, acc, 0, 0, 0);
            acc = __builtin_amdgcn_mfma_f32_16x16x32_bf16(pal, vth, acc, 0, 0, 0);
          }
#pragma unroll
          for (int r = 0; r < 4; ++r)
            AGG[abase + (long)(i0 + kb * 4 + r) * 1568 + jd0 + jl0 + lr] = acc[r];
        }
      }
    }
    __syncthreads();
  }
}

// -------- AGG -> FMAP^T hi/lo bf16 [16][3200][512] ---------------------------------
__global__ __launch_bounds__(256) void k_fmap_T(const float* __restrict__ AGG,
                                                unsigned short* __restrict__ Thi,
                                                unsigned short* __restrict__ Tlo) {
  const int wp = blockIdx.x, bb = blockIdx.y;
  const int Xw = wp >> 3, Yw = wp & 7;
  const int c = threadIdx.x * 2;
  const int hh = c >> 5, d0 = c & 31;
  const long abase = ((long)(bb * 16 + hh) * 64 + wp) * 1568;
  for (int j = 0; j < 49; ++j) {
    float v0 = AGG[abase + j * 32 + d0];
    float v1 = AGG[abase + j * 32 + d0 + 1];
    int hw = (Xw * 7 + j / 7) * 56 + Yw * 7 + j % 7;
    long t = ((long)bb * 3200 + hw) * 512 + c;
    unsigned short h0 = f2bf(v0), h1 = f2bf(v1);
    unsigned short l0 = f2bf(v0 - bf2f(h0)), l1 = f2bf(v1 - bf2f(h1));
    *(unsigned*)&Thi[t] = (unsigned)h0 | ((unsigned)h1 << 16);
    *(unsigned*)&Tlo[t] = (unsigned)l0 | ((unsigned)l1 << 16);
  }
}

__global__ __launch_bounds__(256) void k_padzero(unsigned short* __restrict__ Thi,
                                                 unsigned short* __restrict__ Tlo) {
  const int bb = blockIdx.x;
  for (int e = threadIdx.x; e < 32768; e += 256) {
    long idx = ((long)bb * 3200 + 3136) * 512 + e;
    Thi[idx] = 0;
    Tlo[idx] = 0;
  }
}

// ---------------- launch ----------------
extern "C" void kernel_launch(void* const* d_in, const int* in_sizes, int n_in,
                              void* d_out, int out_size, void* d_ws, size_t ws_size,
                              hipStream_t stream) {
  const float* x     = (const float*)d_in[0];
  const float* w_qkv = (const float*)d_in[1];
  const float* wt    = (const float*)d_in[2];
  const float* lnw   = (const float*)d_in[3];
  const float* lnb   = (const float*)d_in[4];
  const float* w_qk  = (const float*)d_in[5];
  const float* b_qk  = (const float*)d_in[6];
  const float* w_out = (const float*)d_in[7];
  const float* b_out = (const float*)d_in[8];
  float* out = (float*)d_out;
  float* ws  = (float*)d_ws;

  // ws (111.1 MB proven): OUT1 f32 [0, 26,214,400); XT chunk at 21,233,664
  // (overlaps only chunk-3 OUT1 rows, written after gemm-3's last XT read;
  //  overlaps AUX, used only post-loop); AUX at 26,214,400.
  float* OUT1 = ws;
  float* AUX  = ws + 26214400L;
  unsigned short* XThi = (unsigned short*)(ws + 21233664L);
  unsigned short* XTlo = XThi + 6553600L;
  float* G  = AUX;
  float* QK = AUX + 524288L;
  unsigned short* WOhi = (unsigned short*)AUX;           // after G dead
  unsigned short* WOlo = WOhi + 262144L;
  unsigned short* FThi = (unsigned short*)ws;            // after OUT1 dead
  unsigned short* FTlo = FThi + 26214400L;

  // d_out: QKVc packed u32 [0, 19,660,800); Whi/Wlo at f32 offset 19,660,800;
  // AGG = full d_out after chunk loop.
  unsigned* QKVc = (unsigned*)d_out;
  unsigned short* Whi = (unsigned short*)(out + 19660800L);
  unsigned short* Wlo = Whi + 786432L;
  float* AGG = out;

  // 1. split w_qkv -> bf16 hi/lo (d_out tail)
  k_split<<<3072, 256, 0, stream>>>(w_qkv, Whi, Wlo, 786432);
  // 2. per 4-image chunk: gather XcT, QKV MFMA GEMM (packed out), stage-1 attention
  for (int c = 0; c < 4; ++c) {
    k_build_xcT<<<dim3(8, 57, 4), 256, 0, stream>>>(x, wt, XThi, XTlo, c * 4);
    k_gemm_mfma<1><<<dim3(100, 12, 1), 256, 0, stream>>>(Whi, Wlo, XThi, XTlo,
                                                         (float*)QKVc, nullptr,
                                                         12800, 0, 0);
    k_attn1_mfma<<<1024, 256, 0, stream>>>(QKVc, OUT1, c * 256);
  }
  // 3. LN + GELU -> G
  k_ln_gelu<<<2048, 256, 0, stream>>>(OUT1, lnw, lnb, G);
  // 4. qk = w_qk @ G + b_qk
  k_gemm<<<dim3(1, 8, 16), 256, 0, stream>>>(w_qk, G, QK, b_qk,
                                             1024, 64, 512, 512L * 64, 1024L * 64);
  // 5. split w_out (G region dead)
  k_split<<<1024, 256, 0, stream>>>(w_out, WOhi, WOlo, 262144);
  // 6. stage-2 attention + MFMA aggregation -> AGG (d_out; QKVc/W dead)
  k_attn2_mfma<<<dim3(256, 2, 1), 256, 0, stream>>>(QK, OUT1, AGG);
  // 7. AGG -> FMAP^T hi/lo + zero pad rows (overwrites OUT1 region)
  k_fmap_T<<<dim3(64, 16), 256, 0, stream>>>(AGG, FThi, FTlo);
  k_padzero<<<16, 256, 0, stream>>>(FThi, FTlo);
  // 8. out = w_out @ FMAP + b_out (f32 out, batched over 16 images)
  k_gemm_mfma<0><<<dim3(25, 4, 16), 256, 0, stream>>>(WOhi, WOlo, FThi, FTlo, out,
                                                      b_out, 3136, 3200, 512L * 3136);
}

// Round 15
// 782.192 us; speedup vs baseline: 1.1787x; 1.1787x over previous
//
#include <hip/hip_runtime.h>
#include <math.h>

// b=16, C=512, H=W=56, wsz=7, X=Y=8, nw=64/img, n=49, tokens=50, heads=16, dhead=32
#define SCALE_D 0.17677669529663687f  // 32^-0.5

typedef __attribute__((ext_vector_type(8))) short short8;
typedef __attribute__((ext_vector_type(4))) float f32x4;

__device__ __forceinline__ unsigned short f2bf(float f) {
  unsigned u = __builtin_bit_cast(unsigned, f);
  unsigned r = u + 0x7FFF + ((u >> 16) & 1);
  return (unsigned short)(r >> 16);
}
__device__ __forceinline__ float bf2f(unsigned short h) {
  unsigned u = ((unsigned)h) << 16;
  return __builtin_bit_cast(float, u);
}
__device__ __forceinline__ void gload16(const void* g, void* l) {
  __builtin_amdgcn_global_load_lds((const __attribute__((address_space(1))) unsigned int*)g,
                                   (__attribute__((address_space(3))) unsigned int*)l,
                                   16, 0, 0);
}

// -------- split f32 -> bf16 hi/lo planes ------------------------------------------
__global__ __launch_bounds__(256) void k_split(const float* __restrict__ src,
                                               unsigned short* __restrict__ hi,
                                               unsigned short* __restrict__ lo, int n) {
  int i = blockIdx.x * 256 + threadIdx.x;
  if (i < n) {
    float v = src[i];
    unsigned short h = f2bf(v);
    hi[i] = h;
    lo[i] = f2bf(v - bf2f(h));
  }
}

// -------- gather Xc^T chunk (4 images) as bf16 hi/lo [12800][512] ------------------
__global__ __launch_bounds__(256) void k_build_xcT(const float* __restrict__ x,
                                                   const float* __restrict__ wtok,
                                                   unsigned short* __restrict__ Thi,
                                                   unsigned short* __restrict__ Tlo,
                                                   int bb0) {
  const int cblk = blockIdx.x;   // 0..7
  const int h    = blockIdx.y;   // 0..55 pixels, 56 = token-0 pass
  const int bbL  = blockIdx.z;   // 0..3
  const int bb   = bb0 + bbL;
  const int tid  = threadIdx.x;
  const int c0   = cblk * 64;
  if (h == 56) {
    for (int e = tid; e < 4096; e += 256) {
      int wl = e >> 6, cl = e & 63;
      float v = wtok[c0 + cl];
      unsigned short hv = f2bf(v);
      long idx = ((long)(bbL * 64 + wl) * 50) * 512 + c0 + cl;
      Thi[idx] = hv;
      Tlo[idx] = f2bf(v - bf2f(hv));
    }
    return;
  }
  __shared__ unsigned short shi[64][57], slo[64][57];
  const int Xw = h / 7, r7 = h % 7;
  for (int e = tid; e < 3584; e += 256) {
    int cl = e / 56, w = e - cl * 56;
    float v = x[((long)(bb * 512 + c0 + cl) * 56 + h) * 56 + w];
    unsigned short hv = f2bf(v);
    shi[cl][w] = hv;
    slo[cl][w] = f2bf(v - bf2f(hv));
  }
  __syncthreads();
  for (int e = tid; e < 3584; e += 256) {
    int row = e >> 6, cl = e & 63;       // row = Yw*7+c7
    int Yw = row / 7, c7 = row - Yw * 7;
    long trow = (long)(bbL * 64 + Xw * 8 + Yw) * 50 + 1 + r7 * 7 + c7;
    Thi[trow * 512 + c0 + cl] = shi[cl][row];
    Tlo[trow * 512 + c0 + cl] = slo[cl][row];
  }
}

// -------- split-bf16 MFMA GEMM, 128x128, dbuf + counted vmcnt + swizzle -----------
// (proven round-10 structure; used for QKV chunks)
template <int PACK>
__global__ __launch_bounds__(256, 2) void k_gemm_mfma(
    const unsigned short* __restrict__ Ahi, const unsigned short* __restrict__ Alo,
    const unsigned short* __restrict__ Bhi, const unsigned short* __restrict__ Blo,
    float* __restrict__ C, const float* __restrict__ bias,
    int NC, int brow_stride, long c_stride) {
  __shared__ unsigned short lds[2][4][128][32];  // 2 bufs x {Ahi,Alo,Bhi,Blo} = 64 KB
  const int tid = threadIdx.x;
  const int wv = tid >> 6, lane = tid & 63;

  const int gy = gridDim.y;
  const int nwg = gridDim.x * gy;
  int hw = blockIdx.y * gridDim.x + blockIdx.x;
  int flat;
  {
    int q = nwg >> 3, r = nwg & 7;
    int xcd = hw & 7, k = hw >> 3;
    int start = (xcd < r) ? xcd * (q + 1) : r * (q + 1) + (xcd - r) * q;
    flat = start + k;
  }
  const int bx = flat / gy, by = flat % gy;
  const int m0 = by * 128, n0 = bx * 128;
  const long brow0 = (long)blockIdx.z * brow_stride + n0;
  C += (long)blockIdx.z * c_stride;

  const int wr = wv >> 1, wc = wv & 1;
  const int lr = lane & 15, kb = lane >> 4;
  const int srow = lane >> 2, sju = lane & 3;
  const int sswz = (sju ^ ((srow >> 1) & 3)) * 8;
  const int rswz = (lr >> 1) & 3;

  f32x4 acc[4][4];
#pragma unroll
  for (int i = 0; i < 4; ++i)
#pragma unroll
    for (int j = 0; j < 4; ++j) {
      f32x4 z = {0.f, 0.f, 0.f, 0.f};
      acc[i][j] = z;
    }

  auto STAGE = [&](int buf, int k0) {
#pragma unroll
    for (int it = 0; it < 2; ++it) {
      const int rloc = (wv * 2 + it) * 16;
      const int r = rloc + srow;
      const long ga = (long)(m0 + r) * 512 + k0 + sswz;
      gload16(Ahi + ga, &lds[buf][0][rloc][0]);
      gload16(Alo + ga, &lds[buf][1][rloc][0]);
      const long gb = (brow0 + r) * 512 + k0 + sswz;
      gload16(Bhi + gb, &lds[buf][2][rloc][0]);
      gload16(Blo + gb, &lds[buf][3][rloc][0]);
    }
  };

  STAGE(0, 0);
  int cur = 0;
  for (int t = 0; t < 16; ++t) {
    if (t < 15) STAGE(cur ^ 1, (t + 1) * 32);
    if (t < 15) {
      asm volatile("s_waitcnt vmcnt(8)" ::: "memory");
    } else {
      asm volatile("s_waitcnt vmcnt(0)" ::: "memory");
    }
    __builtin_amdgcn_s_barrier();
    asm volatile("" ::: "memory");
    short8 ah[4], al[4], bh[4], bl[4];
#pragma unroll
    for (int f = 0; f < 4; ++f) {
      int ra = wr * 64 + f * 16 + lr;
      int ca = (kb ^ rswz) * 8;
      ah[f] = *(const short8*)&lds[cur][0][ra][ca];
      al[f] = *(const short8*)&lds[cur][1][ra][ca];
      int rb = wc * 64 + f * 16 + lr;
      bh[f] = *(const short8*)&lds[cur][2][rb][ca];
      bl[f] = *(const short8*)&lds[cur][3][rb][ca];
    }
#pragma unroll
    for (int i = 0; i < 4; ++i)
#pragma unroll
      for (int j = 0; j < 4; ++j) {
        acc[i][j] = __builtin_amdgcn_mfma_f32_16x16x32_bf16(ah[i], bh[j], acc[i][j], 0, 0, 0);
        acc[i][j] = __builtin_amdgcn_mfma_f32_16x16x32_bf16(ah[i], bl[j], acc[i][j], 0, 0, 0);
        acc[i][j] = __builtin_amdgcn_mfma_f32_16x16x32_bf16(al[i], bh[j], acc[i][j], 0, 0, 0);
      }
    asm volatile("s_waitcnt lgkmcnt(0)" ::: "memory");
    __builtin_amdgcn_s_barrier();
    asm volatile("" ::: "memory");
    cur ^= 1;
  }

#pragma unroll
  for (int i = 0; i < 4; ++i)
#pragma unroll
    for (int nf = 0; nf < 4; ++nf) {
      int col = n0 + wc * 64 + nf * 16 + lr;
      if (col < NC) {
#pragma unroll
        for (int j4 = 0; j4 < 4; ++j4) {
          int row = m0 + wr * 64 + i * 16 + kb * 4 + j4;
          float v = acc[i][nf][j4];
          if (PACK) {
            unsigned short h = f2bf(v);
            unsigned short l = f2bf(v - bf2f(h));
            ((unsigned*)C)[(long)row * NC + col] = (unsigned)h | ((unsigned)l << 16);
          } else {
            C[(long)row * NC + col] = v + (bias ? bias[row] : 0.f);
          }
        }
      }
    }
}

// -------- 256x256 8-wave GEMM, 4-phase schedule (T3+T4+T5) — final GEMM -----------
__global__ __launch_bounds__(512, 2) void k_gemm_mfma8p(
    const unsigned short* __restrict__ Ahi, const unsigned short* __restrict__ Alo,
    const unsigned short* __restrict__ Bhi, const unsigned short* __restrict__ Blo,
    float* __restrict__ C, const float* __restrict__ bias,
    int NC, int brow_stride, long c_stride) {
  __shared__ unsigned short lds[2][4][256][32];  // 128 KB
  const int tid = threadIdx.x;
  const int wv = tid >> 6, lane = tid & 63;

  const int gy = gridDim.y;
  const int nwg = gridDim.x * gy;
  int hw = blockIdx.y * gridDim.x + blockIdx.x;
  int flat;
  {
    int q = nwg >> 3, r = nwg & 7;
    int xcd = hw & 7, k = hw >> 3;
    int start = (xcd < r) ? xcd * (q + 1) : r * (q + 1) + (xcd - r) * q;
    flat = start + k;
  }
  const int bx = flat / gy, by = flat % gy;
  const int m0 = by * 256, n0 = bx * 256;
  const long brow0 = (long)blockIdx.z * brow_stride + n0;
  C += (long)blockIdx.z * c_stride;

  const int wr = wv >> 2, wc = wv & 3;        // 2m x 4n wave grid
  const int lr = lane & 15, kb = lane >> 4;
  const int srow = lane >> 2, sju = lane & 3;
  const int sswz = (sju ^ ((srow >> 1) & 3)) * 8;
  const int ca = (kb ^ ((lr >> 1) & 3)) * 8;

  f32x4 acc[8][4];
#pragma unroll
  for (int i = 0; i < 8; ++i)
#pragma unroll
    for (int j = 0; j < 4; ++j) {
      f32x4 z = {0.f, 0.f, 0.f, 0.f};
      acc[i][j] = z;
    }

  auto STAGE4 = [&](int buf, int k0, int it) {
    const int rloc = wv * 32 + it * 16;
    const int r = rloc + srow;
    const long ga = (long)(m0 + r) * 512 + k0 + sswz;
    gload16(Ahi + ga, &lds[buf][0][rloc][0]);
    gload16(Alo + ga, &lds[buf][1][rloc][0]);
    const long gb = (brow0 + r) * 512 + k0 + sswz;
    gload16(Bhi + gb, &lds[buf][2][rloc][0]);
    gload16(Blo + gb, &lds[buf][3][rloc][0]);
  };

  STAGE4(0, 0, 0);
  STAGE4(0, 0, 1);
  asm volatile("s_waitcnt vmcnt(0)" ::: "memory");
  __builtin_amdgcn_s_barrier();

  int cur = 0;
  for (int t = 0; t < 16; ++t) {
    short8 bh[4], bl[4];
#pragma unroll
    for (int q = 0; q < 4; ++q) {
      if (t < 15 && q < 2) STAGE4(cur ^ 1, (t + 1) * 32, q);  // loads span phases
      if (q == 0) {
#pragma unroll
        for (int nt = 0; nt < 4; ++nt) {      // B-frags once per tile, reg-resident
          int rb = wc * 64 + nt * 16 + lr;
          bh[nt] = *(const short8*)&lds[cur][2][rb][ca];
          bl[nt] = *(const short8*)&lds[cur][3][rb][ca];
        }
      }
      const int ra0 = wr * 128 + (q * 2 + 0) * 16 + lr;
      const int ra1 = wr * 128 + (q * 2 + 1) * 16 + lr;
      const short8 ah0 = *(const short8*)&lds[cur][0][ra0][ca];
      const short8 al0 = *(const short8*)&lds[cur][1][ra0][ca];
      const short8 ah1 = *(const short8*)&lds[cur][0][ra1][ca];
      const short8 al1 = *(const short8*)&lds[cur][1][ra1][ca];
      __builtin_amdgcn_sched_barrier(0);      // reads issued before the barrier
      __builtin_amdgcn_s_barrier();
      asm volatile("s_waitcnt lgkmcnt(0)" ::: "memory");
      __builtin_amdgcn_sched_barrier(0);      // rule 18: fence before reg-only MFMA
      __builtin_amdgcn_s_setprio(1);
#pragma unroll
      for (int nt = 0; nt < 4; ++nt) {
        acc[q * 2 + 0][nt] =
            __builtin_amdgcn_mfma_f32_16x16x32_bf16(ah0, bh[nt], acc[q * 2 + 0][nt], 0, 0, 0);
        acc[q * 2 + 0][nt] =
            __builtin_amdgcn_mfma_f32_16x16x32_bf16(ah0, bl[nt], acc[q * 2 + 0][nt], 0, 0, 0);
        acc[q * 2 + 0][nt] =
            __builtin_amdgcn_mfma_f32_16x16x32_bf16(al0, bh[nt], acc[q * 2 + 0][nt], 0, 0, 0);
        acc[q * 2 + 1][nt] =
            __builtin_amdgcn_mfma_f32_16x16x32_bf16(ah1, bh[nt], acc[q * 2 + 1][nt], 0, 0, 0);
        acc[q * 2 + 1][nt] =
            __builtin_amdgcn_mfma_f32_16x16x32_bf16(ah1, bl[nt], acc[q * 2 + 1][nt], 0, 0, 0);
        acc[q * 2 + 1][nt] =
            __builtin_amdgcn_mfma_f32_16x16x32_bf16(al1, bh[nt], acc[q * 2 + 1][nt], 0, 0, 0);
      }
      __builtin_amdgcn_s_setprio(0);
      __builtin_amdgcn_sched_barrier(0);
      if (q < 3) __builtin_amdgcn_s_barrier();
    }
    __syncthreads();   // tile boundary: drain vm+lgkm (loads issued >=2 phases ago)
    cur ^= 1;
  }

#pragma unroll
  for (int mt = 0; mt < 8; ++mt)
#pragma unroll
    for (int nt = 0; nt < 4; ++nt) {
      int col = n0 + wc * 64 + nt * 16 + lr;
      if (col < NC) {
#pragma unroll
        for (int j4 = 0; j4 < 4; ++j4) {
          int row = m0 + wr * 128 + mt * 16 + kb * 4 + j4;
          C[(long)row * NC + col] = acc[mt][nt][j4] + (bias ? bias[row] : 0.f);
        }
      }
    }
}

// -------- stage-1 attention, MFMA, one wave per (window, head) ---------------------
__global__ __launch_bounds__(256) void k_attn1_mfma(const unsigned* __restrict__ QKV,
                                                    float* __restrict__ OUT1, int w0) {
  __shared__ unsigned short P[4][16][72];
  const int tid = threadIdx.x;
  const int wv = tid >> 6, lane = tid & 63;
  const int idx = blockIdx.x * 4 + wv;     // wl*16 + h
  const int wl = idx >> 4, h = idx & 15;
  const int lr = lane & 15, kb = lane >> 4;
  const long tb = (long)wl * 50;

  short8 kh[4], kl[4];
#pragma unroll
  for (int jt = 0; jt < 4; ++jt) {
#pragma unroll
    for (int e = 0; e < 8; ++e) {
      unsigned u = QKV[(long)(512 + h * 32 + kb * 8 + e) * 12800 + tb + jt * 16 + lr];
      kh[jt][e] = (short)(u & 0xFFFF);
      kl[jt][e] = (short)(u >> 16);
    }
  }
  short8 vh[2][2], vl[2][2];
#pragma unroll
  for (int ddt = 0; ddt < 2; ++ddt)
#pragma unroll
    for (int ks = 0; ks < 2; ++ks) {
      const long vb = (long)(1024 + h * 32 + ddt * 16 + lr) * 12800 + tb + ks * 32 + kb * 8;
#pragma unroll
      for (int e = 0; e < 8; ++e) {
        int j = ks * 32 + kb * 8 + e;
        unsigned u = (j < 50) ? QKV[vb + e] : 0u;
        vh[ddt][ks][e] = (short)(u & 0xFFFF);
        vl[ddt][ks][e] = (short)(u >> 16);
      }
    }

  const long ob = (long)((w0 + wl) * 16 + h) * 1600;

  for (int it = 0; it < 4; ++it) {
    short8 qh, ql;
#pragma unroll
    for (int e = 0; e < 8; ++e) {
      unsigned u = QKV[(long)(h * 32 + kb * 8 + e) * 12800 + tb + it * 16 + lr];
      qh[e] = (short)(u & 0xFFFF);
      ql[e] = (short)(u >> 16);
    }
    f32x4 s[4];
#pragma unroll
    for (int jt = 0; jt < 4; ++jt) {
      f32x4 z = {0.f, 0.f, 0.f, 0.f};
      s[jt] = z;
      s[jt] = __builtin_amdgcn_mfma_f32_16x16x32_bf16(qh, kh[jt], s[jt], 0, 0, 0);
      s[jt] = __builtin_amdgcn_mfma_f32_16x16x32_bf16(qh, kl[jt], s[jt], 0, 0, 0);
      s[jt] = __builtin_amdgcn_mfma_f32_16x16x32_bf16(ql, kh[jt], s[jt], 0, 0, 0);
#pragma unroll
      for (int r = 0; r < 4; ++r) s[jt][r] *= SCALE_D;
    }
    if (lr >= 2) {
#pragma unroll
      for (int r = 0; r < 4; ++r) s[3][r] = -1e30f;
    }
    float ex[4][4], rinv[4];
#pragma unroll
    for (int r = 0; r < 4; ++r) {
      float m = fmaxf(fmaxf(s[0][r], s[1][r]), fmaxf(s[2][r], s[3][r]));
      m = fmaxf(m, __shfl_xor(m, 1));
      m = fmaxf(m, __shfl_xor(m, 2));
      m = fmaxf(m, __shfl_xor(m, 4));
      m = fmaxf(m, __shfl_xor(m, 8));
      float sm = 0.f;
#pragma unroll
      for (int jt = 0; jt < 4; ++jt) {
        ex[jt][r] = __expf(s[jt][r] - m);
        sm += ex[jt][r];
      }
      sm += __shfl_xor(sm, 1);
      sm += __shfl_xor(sm, 2);
      sm += __shfl_xor(sm, 4);
      sm += __shfl_xor(sm, 8);
      rinv[r] = 1.f / sm;
    }
#pragma unroll
    for (int jt = 0; jt < 4; ++jt)
#pragma unroll
      for (int r = 0; r < 4; ++r)
        P[wv][kb * 4 + r][jt * 16 + lr] = f2bf(ex[jt][r] * rinv[r]);
    short8 pa0 = *(const short8*)&P[wv][lr][kb * 8];
    short8 pa1 = *(const short8*)&P[wv][lr][32 + kb * 8];
    f32x4 o[2];
#pragma unroll
    for (int ddt = 0; ddt < 2; ++ddt) {
      f32x4 z = {0.f, 0.f, 0.f, 0.f};
      o[ddt] = z;
      o[ddt] = __builtin_amdgcn_mfma_f32_16x16x32_bf16(pa0, vh[ddt][0], o[ddt], 0, 0, 0);
      o[ddt] = __builtin_amdgcn_mfma_f32_16x16x32_bf16(pa0, vl[ddt][0], o[ddt], 0, 0, 0);
      o[ddt] = __builtin_amdgcn_mfma_f32_16x16x32_bf16(pa1, vh[ddt][1], o[ddt], 0, 0, 0);
      o[ddt] = __builtin_amdgcn_mfma_f32_16x16x32_bf16(pa1, vl[ddt][1], o[ddt], 0, 0, 0);
    }
#pragma unroll
    for (int ddt = 0; ddt < 2; ++ddt)
#pragma unroll
      for (int r = 0; r < 4; ++r) {
        int i = it * 16 + kb * 4 + r;
        if (i < 50) OUT1[ob + i * 32 + ddt * 16 + lr] = o[ddt][r];
      }
  }
}

// -------- f32 GEMM (small qk projection) -------------------------------------------
__global__ __launch_bounds__(256) void k_gemm(const float* __restrict__ A,
                                              const float* __restrict__ Bg,
                                              float* __restrict__ C,
                                              const float* __restrict__ bias,
                                              int M, int N, int K, long sB, long sC) {
  Bg += (long)blockIdx.z * sB;
  C  += (long)blockIdx.z * sC;
  __shared__ __align__(16) float As[32][132];
  __shared__ __align__(16) float Bs[32][132];
  const int tid = threadIdx.x;
  const int tx = tid & 15, ty = tid >> 4;
  const int m0 = blockIdx.y * 128, n0 = blockIdx.x * 128;

  float acc[8][8];
#pragma unroll
  for (int q = 0; q < 8; ++q)
#pragma unroll
    for (int r = 0; r < 8; ++r) acc[q][r] = 0.f;

  for (int k0 = 0; k0 < K; k0 += 32) {
#pragma unroll
    for (int it = 0; it < 4; ++it) {
      int idx = tid + it * 256;
      int row = idx >> 3, c4 = idx & 7;
      const float4 f = *(const float4*)&A[(long)(m0 + row) * K + k0 + c4 * 4];
      As[c4 * 4 + 0][row] = f.x;
      As[c4 * 4 + 1][row] = f.y;
      As[c4 * 4 + 2][row] = f.z;
      As[c4 * 4 + 3][row] = f.w;
    }
#pragma unroll
    for (int it = 0; it < 4; ++it) {
      int idx = tid + it * 256;
      int row = idx >> 5, c4 = idx & 31;
      int col = n0 + c4 * 4;
      float4 f;
      if (col + 3 < N) {
        f = *(const float4*)&Bg[(long)(k0 + row) * N + col];
      } else {
        f.x = (col + 0 < N) ? Bg[(long)(k0 + row) * N + col + 0] : 0.f;
        f.y = (col + 1 < N) ? Bg[(long)(k0 + row) * N + col + 1] : 0.f;
        f.z = (col + 2 < N) ? Bg[(long)(k0 + row) * N + col + 2] : 0.f;
        f.w = (col + 3 < N) ? Bg[(long)(k0 + row) * N + col + 3] : 0.f;
      }
      *(float4*)&Bs[row][c4 * 4] = f;
    }
    __syncthreads();
#pragma unroll
    for (int kk = 0; kk < 32; ++kk) {
      const float4 a0 = *(const float4*)&As[kk][ty * 8];
      const float4 a1 = *(const float4*)&As[kk][ty * 8 + 4];
      const float4 b0 = *(const float4*)&Bs[kk][tx * 8];
      const float4 b1 = *(const float4*)&Bs[kk][tx * 8 + 4];
      const float am[8] = {a0.x, a0.y, a0.z, a0.w, a1.x, a1.y, a1.z, a1.w};
      const float bn[8] = {b0.x, b0.y, b0.z, b0.w, b1.x, b1.y, b1.z, b1.w};
#pragma unroll
      for (int q = 0; q < 8; ++q)
#pragma unroll
        for (int r = 0; r < 8; ++r) acc[q][r] += am[q] * bn[r];
    }
    __syncthreads();
  }

#pragma unroll
  for (int q = 0; q < 8; ++q) {
    int m = m0 + ty * 8 + q;
    float bv = bias ? bias[m] : 0.f;
#pragma unroll
    for (int half = 0; half < 8; half += 4) {
      int col = n0 + tx * 8 + half;
#pragma unroll
      for (int rr = 0; rr < 4; ++rr)
        if (col + rr < N) C[(long)m * N + col + rr] = acc[q][half + rr] + bv;
    }
  }
}

// -------- LayerNorm + exact GELU on window tokens ----------------------------------
__global__ __launch_bounds__(256) void k_ln_gelu(const float* __restrict__ OUT1,
                                                 const float* __restrict__ lnw,
                                                 const float* __restrict__ lnb,
                                                 float* __restrict__ G) {
  const int tid = threadIdx.x;
  const int r = blockIdx.x * 8 + (tid >> 5);
  const int l = tid & 31;
  const int bb = r >> 10, hh = (r >> 6) & 15, wp = r & 63;
  float v = OUT1[((long)((bb * 64 + wp) * 16 + hh)) * 1600 + l];
  float s = v, s2 = v * v;
#pragma unroll
  for (int o = 16; o >= 1; o >>= 1) {
    s += __shfl_xor(s, o, 32);
    s2 += __shfl_xor(s2, o, 32);
  }
  float mu = s * (1.f / 32.f);
  float var = s2 * (1.f / 32.f) - mu * mu;
  float xn = (v - mu) * rsqrtf(var + 1e-5f) * lnw[l] + lnb[l];
  float g = 0.5f * xn * (1.f + erff(xn * 0.70710678118654752f));
  G[((long)(bb * 512 + hh * 32 + l)) * 64 + wp] = g;
}

// -------- stage-2 attention + MFMA aggregation -------------------------------------
__global__ __launch_bounds__(256) void k_attn2_mfma(const float* __restrict__ QK,
                                                    const float* __restrict__ OUT1,
                                                    float* __restrict__ AGG) {
  const int bh = blockIdx.x;
  const int bb = bh >> 4, hh = bh & 15;
  const int tid = threadIdx.x;
  const int wv = tid >> 6, lane = tid & 63;
  const int lr = lane & 15, kb = lane >> 4;
  const int wr = wv >> 1, wc = wv & 1;

  __shared__ float wqs[64 * 33], wks[64 * 33];
  __shared__ float sd[64 * 65];
  __shared__ float smx[64], ssum[64];
  __shared__ __align__(16) unsigned short PAh[64][72], PAl[64][72];  // P[i][wp]
  __shared__ __align__(16) unsigned short VTh[64][72], VTl[64][72];  // V^T[jd][wp]

  for (int t = tid; t < 2048; t += 256) {
    int dd = t >> 6, i = t & 63;
    wqs[i * 33 + dd] = QK[((long)(bb * 1024 + hh * 64 + dd)) * 64 + i] * SCALE_D;
    wks[i * 33 + dd] = QK[((long)(bb * 1024 + hh * 64 + 32 + dd)) * 64 + i];
  }
  __syncthreads();
  for (int t = tid; t < 4096; t += 256) {
    int i = t >> 6, j = t & 63;
    float s = 0.f;
#pragma unroll
    for (int dd = 0; dd < 32; ++dd) s += wqs[i * 33 + dd] * wks[j * 33 + dd];
    sd[i * 65 + j] = s;
  }
  __syncthreads();
  if (tid < 64) {
    float mx = -1e30f;
    for (int j = 0; j < 64; ++j) mx = fmaxf(mx, sd[tid * 65 + j]);
    float sm = 0.f;
    for (int j = 0; j < 64; ++j) sm += expf(sd[tid * 65 + j] - mx);
    smx[tid] = mx;
    ssum[tid] = 1.f / sm;
  }
  __syncthreads();
  for (int t = tid; t < 4096; t += 256) {
    int i = t >> 6, j = t & 63;
    float p = expf(sd[i * 65 + j] - smx[i]) * ssum[i];
    unsigned short h = f2bf(p);
    PAh[i][j] = h;
    PAl[i][j] = f2bf(p - bf2f(h));
  }
  __syncthreads();

  const int jstart = blockIdx.y * 13;                 // y=0: 0..12, y=1: 13..24
  const int ntiles = (blockIdx.y == 0) ? 13 : 12;
  const int swp = tid >> 2, sq = tid & 3;
  const long vbase = ((long)((bb * 64 + swp) * 16 + hh)) * 1600 + 32;
  const long abase = (long)bh * 100352;

  for (int tt = 0; tt < ntiles; ++tt) {
    const int jt = jstart + tt;
    const int jd0 = jt * 64;
    const int JT = (jt == 24) ? 32 : 64;
    for (int jj = 0; jj < (JT >> 4); ++jj) {
      const float4 v4 = *(const float4*)&OUT1[vbase + jd0 + jj * 16 + sq * 4];
#pragma unroll
      for (int e = 0; e < 4; ++e) {
        int jl = jj * 16 + sq * 4 + e;
        float v = (e == 0) ? v4.x : (e == 1) ? v4.y : (e == 2) ? v4.z : v4.w;
        unsigned short h = f2bf(v);
        VTh[jl][swp] = h;
        VTl[jl][swp] = f2bf(v - bf2f(h));
      }
    }
    __syncthreads();
#pragma unroll
    for (int mt = 0; mt < 2; ++mt) {
      const int i0 = wr * 32 + mt * 16;
#pragma unroll
      for (int nt = 0; nt < 2; ++nt) {
        const int jl0 = wc * 32 + nt * 16;
        if (jl0 < JT) {
          f32x4 acc = {0.f, 0.f, 0.f, 0.f};
#pragma unroll
          for (int ks = 0; ks < 2; ++ks) {
            const short8 pah = *(const short8*)&PAh[i0 + lr][ks * 32 + kb * 8];
            const short8 pal = *(const short8*)&PAl[i0 + lr][ks * 32 + kb * 8];
            const short8 vth = *(const short8*)&VTh[jl0 + lr][ks * 32 + kb * 8];
            const short8 vtl = *(const short8*)&VTl[jl0 + lr][ks * 32 + kb * 8];
            acc = __builtin_amdgcn_mfma_f32_16x16x32_bf16(pah, vth, acc, 0, 0, 0);
            acc = __builtin_amdgcn_mfma_f32_16x16x32_bf16(pah, vtl, acc, 0, 0, 0);
            acc = __builtin_amdgcn_mfma_f32_16x16x32_bf16(pal, vth, acc, 0, 0, 0);
          }
#pragma unroll
          for (int r = 0; r < 4; ++r)
            AGG[abase + (long)(i0 + kb * 4 + r) * 1568 + jd0 + jl0 + lr] = acc[r];
        }
      }
    }
    __syncthreads();
  }
}

// -------- AGG -> FMAP^T hi/lo bf16 [16][3200][512] ---------------------------------
__global__ __launch_bounds__(256) void k_fmap_T(const float* __restrict__ AGG,
                                                unsigned short* __restrict__ Thi,
                                                unsigned short* __restrict__ Tlo) {
  const int wp = blockIdx.x, bb = blockIdx.y;
  const int Xw = wp >> 3, Yw = wp & 7;
  const int c = threadIdx.x * 2;
  const int hh = c >> 5, d0 = c & 31;
  const long abase = ((long)(bb * 16 + hh) * 64 + wp) * 1568;
  for (int j = 0; j < 49; ++j) {
    float v0 = AGG[abase + j * 32 + d0];
    float v1 = AGG[abase + j * 32 + d0 + 1];
    int hw = (Xw * 7 + j / 7) * 56 + Yw * 7 + j % 7;
    long t = ((long)bb * 3200 + hw) * 512 + c;
    unsigned short h0 = f2bf(v0), h1 = f2bf(v1);
    unsigned short l0 = f2bf(v0 - bf2f(h0)), l1 = f2bf(v1 - bf2f(h1));
    *(unsigned*)&Thi[t] = (unsigned)h0 | ((unsigned)h1 << 16);
    *(unsigned*)&Tlo[t] = (unsigned)l0 | ((unsigned)l1 << 16);
  }
}

__global__ __launch_bounds__(256) void k_padzero(unsigned short* __restrict__ Thi,
                                                 unsigned short* __restrict__ Tlo) {
  const int bb = blockIdx.x;
  for (int e = threadIdx.x; e < 32768; e += 256) {
    long idx = ((long)bb * 3200 + 3136) * 512 + e;
    Thi[idx] = 0;
    Tlo[idx] = 0;
  }
}

// ---------------- launch ----------------
extern "C" void kernel_launch(void* const* d_in, const int* in_sizes, int n_in,
                              void* d_out, int out_size, void* d_ws, size_t ws_size,
                              hipStream_t stream) {
  const float* x     = (const float*)d_in[0];
  const float* w_qkv = (const float*)d_in[1];
  const float* wt    = (const float*)d_in[2];
  const float* lnw   = (const float*)d_in[3];
  const float* lnb   = (const float*)d_in[4];
  const float* w_qk  = (const float*)d_in[5];
  const float* b_qk  = (const float*)d_in[6];
  const float* w_out = (const float*)d_in[7];
  const float* b_out = (const float*)d_in[8];
  float* out = (float*)d_out;
  float* ws  = (float*)d_ws;

  // ws (111.1 MB proven): OUT1 f32 [0, 26,214,400); XT chunk at 21,233,664
  // (overlaps only chunk-3 OUT1 rows, written after gemm-3's last XT read;
  //  overlaps AUX, used only post-loop); AUX at 26,214,400.
  float* OUT1 = ws;
  float* AUX  = ws + 26214400L;
  unsigned short* XThi = (unsigned short*)(ws + 21233664L);
  unsigned short* XTlo = XThi + 6553600L;
  float* G  = AUX;
  float* QK = AUX + 524288L;
  unsigned short* WOhi = (unsigned short*)AUX;           // after G dead
  unsigned short* WOlo = WOhi + 262144L;
  unsigned short* FThi = (unsigned short*)ws;            // after OUT1 dead
  unsigned short* FTlo = FThi + 26214400L;

  // d_out: QKVc packed u32 [0, 19,660,800); Whi/Wlo at f32 offset 19,660,800;
  // AGG = full d_out after chunk loop.
  unsigned* QKVc = (unsigned*)d_out;
  unsigned short* Whi = (unsigned short*)(out + 19660800L);
  unsigned short* Wlo = Whi + 786432L;
  float* AGG = out;

  // 1. split w_qkv -> bf16 hi/lo (d_out tail)
  k_split<<<3072, 256, 0, stream>>>(w_qkv, Whi, Wlo, 786432);
  // 2. per 4-image chunk: gather XcT, QKV MFMA GEMM (packed out), stage-1 attention
  for (int c = 0; c < 4; ++c) {
    k_build_xcT<<<dim3(8, 57, 4), 256, 0, stream>>>(x, wt, XThi, XTlo, c * 4);
    k_gemm_mfma<1><<<dim3(100, 12, 1), 256, 0, stream>>>(Whi, Wlo, XThi, XTlo,
                                                         (float*)QKVc, nullptr,
                                                         12800, 0, 0);
    k_attn1_mfma<<<1024, 256, 0, stream>>>(QKVc, OUT1, c * 256);
  }
  // 3. LN + GELU -> G
  k_ln_gelu<<<2048, 256, 0, stream>>>(OUT1, lnw, lnb, G);
  // 4. qk = w_qk @ G + b_qk
  k_gemm<<<dim3(1, 8, 16), 256, 0, stream>>>(w_qk, G, QK, b_qk,
                                             1024, 64, 512, 512L * 64, 1024L * 64);
  // 5. split w_out (G region dead)
  k_split<<<1024, 256, 0, stream>>>(w_out, WOhi, WOlo, 262144);
  // 6. stage-2 attention + MFMA aggregation -> AGG (d_out; QKVc/W dead)
  k_attn2_mfma<<<dim3(256, 2, 1), 256, 0, stream>>>(QK, OUT1, AGG);
  // 7. AGG -> FMAP^T hi/lo + zero pad rows (overwrites OUT1 region)
  k_fmap_T<<<dim3(64, 16), 256, 0, stream>>>(AGG, FThi, FTlo);
  k_padzero<<<16, 256, 0, stream>>>(FThi, FTlo);
  // 8. out = w_out @ FMAP + b_out — 256² 4-phase schedule
  //    (B rows past 3200/image read in-bounds garbage; discarded by col<NC guard)
  k_gemm_mfma8p<<<dim3(13, 2, 16), 512, 0, stream>>>(WOhi, WOlo, FThi, FTlo, out,
                                                     b_out, 3136, 3200, 512L * 3136);
}